// Round 1
// baseline (528.435 us; speedup 1.0000x reference)
//
#include <hip/hip_runtime.h>

#define NN 8192
#define FIN 128
#define FOUT 64
#define NEGINF (-9e15f)
#define LALPHA 0.2f

typedef float f32x4 __attribute__((ext_vector_type(4)));
typedef short short8 __attribute__((ext_vector_type(8)));

__device__ __forceinline__ unsigned short f32_to_bf16(float x) {
  unsigned int u = __float_as_uint(x);
  u = (u + 0x7fffu + ((u >> 16) & 1u)) >> 16;
  return (unsigned short)u;
}
__device__ __forceinline__ float bf16_to_f32(unsigned short b) {
  return __uint_as_float(((unsigned int)b) << 16);
}

// Kernel A: Wh = h@W (fp32), s1 = Wh@a1, s2 = Wh@a2, and Wh pre-swizzled into
// MFMA B-fragment layout (bf16 hi) so the main kernel's B loads are coalesced.
__global__ __launch_bounds__(256) void gat_prep(
    const float* __restrict__ h, const float* __restrict__ W,
    const float* __restrict__ a,
    float* __restrict__ s1g, float* __restrict__ s2g,
    unsigned short* __restrict__ whfh)
{
  __shared__ __align__(16) float Wl[FIN * FOUT];
  __shared__ __align__(16) float hl[16 * FIN];
  const int tid = threadIdx.x;
  const int i0 = blockIdx.x * 16;
  #pragma unroll
  for (int it = 0; it < 8; ++it) {
    int idx = (it * 256 + tid) * 4;
    *(f32x4*)&Wl[idx] = *(const f32x4*)&W[idx];
  }
  #pragma unroll
  for (int it = 0; it < 2; ++it) {
    int idx = (it * 256 + tid) * 4;
    *(f32x4*)&hl[idx] = *(const f32x4*)&h[(size_t)i0 * FIN + idx];
  }
  __syncthreads();
  const int r = tid >> 4;
  const int f0 = (tid & 15) * 4;
  f32x4 acc = {0.f, 0.f, 0.f, 0.f};
  #pragma unroll 8
  for (int k = 0; k < FIN; ++k) {
    float hv = hl[r * FIN + k];
    f32x4 wv = *(const f32x4*)&Wl[k * FOUT + f0];
    acc += hv * wv;
  }
  f32x4 a1v = *(const f32x4*)&a[f0];
  f32x4 a2v = *(const f32x4*)&a[FOUT + f0];
  float p1 = acc.x * a1v.x + acc.y * a1v.y + acc.z * a1v.z + acc.w * a1v.w;
  float p2 = acc.x * a2v.x + acc.y * a2v.y + acc.z * a2v.z + acc.w * a2v.w;
  #pragma unroll
  for (int d = 1; d < 16; d <<= 1) {
    p1 += __shfl_xor(p1, d, 16);
    p2 += __shfl_xor(p2, d, 16);
  }
  const int j = i0 + r;  // row of Wh == K index of PV
  if ((tid & 15) == 0) { s1g[j] = p1; s2g[j] = p2; }
  // B-fragment layout for mfma_f32_16x16x32_bf16:
  // value Wh[k][n] -> frag[(kstep*4 + n/16)*512 + (((k%32)/8)*16 + n%16)*8 + k%8]
  const int kstep = j >> 5;
  const int lhi = (j >> 3) & 3;
  const int ein = j & 7;
  #pragma unroll
  for (int e = 0; e < 4; ++e) {
    int f = f0 + e;
    unsigned short hb = f32_to_bf16(acc[e]);
    int ln = lhi * 16 + (f & 15);
    whfh[(size_t)(kstep * 4 + (f >> 4)) * 512 + ln * 8 + ein] = hb;
  }
}

// Kernel B: per block, 16 rows. Phase 1: one pass over adj builds bitmask in
// LDS + row max (monotonicity: m = lrelu(s1 + max_neighbors s2)), then l from
// LDS only. Phase 2: 4 waves K-split; each wave computes its attn values in
// registers (exact fp32, written nontemporal), converts to bf16 hi+lo A-frags
// and accumulates PV via 2 MFMAs per N-tile. Cross-wave reduce at the end.
__global__ __launch_bounds__(256, 2) void gat_main(
    const int* __restrict__ adj,
    const float* __restrict__ s1g, const float* __restrict__ s2g,
    const unsigned short* __restrict__ whfh,
    float* __restrict__ outh, float* __restrict__ outa)
{
  __shared__ __align__(16) float s2l[NN];                // 32 KB
  __shared__ __align__(16) unsigned int maskl[16][257];  // 16.4 KB (pad: conflict-free)
  __shared__ float rowp[16][4];                          // s1, m, 1/l
  const int tid = threadIdx.x;
  const int lane = tid & 63;
  const int wv = tid >> 6;
  const int i0 = blockIdx.x * 16;

  #pragma unroll
  for (int it = 0; it < 8; ++it) {
    int idx = (it * 256 + tid) * 4;
    *(f32x4*)&s2l[idx] = *(const f32x4*)&s2g[idx];
  }
  __syncthreads();

  // ---------------- phase 1: mask + m + l (wave wv owns rows 4wv..4wv+3) ----
  {
    const int rbase = wv * 4;
    const int* __restrict__ ar0 = adj + (size_t)(i0 + rbase + 0) * NN;
    const int* __restrict__ ar1 = adj + (size_t)(i0 + rbase + 1) * NN;
    const int* __restrict__ ar2 = adj + (size_t)(i0 + rbase + 2) * NN;
    const int* __restrict__ ar3 = adj + (size_t)(i0 + rbase + 3) * NN;
    float mx0 = -3.4e38f, mx1 = -3.4e38f, mx2 = -3.4e38f, mx3 = -3.4e38f;
    #pragma unroll 2
    for (int it = 0; it < 128; ++it) {
      int jj = it * 64 + lane;
      float sv = s2l[jj];
      int a0 = __builtin_nontemporal_load(&ar0[jj]);
      int a1 = __builtin_nontemporal_load(&ar1[jj]);
      int a2 = __builtin_nontemporal_load(&ar2[jj]);
      int a3 = __builtin_nontemporal_load(&ar3[jj]);
      unsigned long long b0 = __ballot(a0 > 0);
      unsigned long long b1 = __ballot(a1 > 0);
      unsigned long long b2 = __ballot(a2 > 0);
      unsigned long long b3 = __ballot(a3 > 0);
      mx0 = fmaxf(mx0, (a0 > 0) ? sv : -3.4e38f);
      mx1 = fmaxf(mx1, (a1 > 0) ? sv : -3.4e38f);
      mx2 = fmaxf(mx2, (a2 > 0) ? sv : -3.4e38f);
      mx3 = fmaxf(mx3, (a3 > 0) ? sv : -3.4e38f);
      if ((lane & 31) == 0) {
        int hi = lane >> 5;
        maskl[rbase + 0][it * 2 + hi] = (unsigned int)(b0 >> (hi * 32));
        maskl[rbase + 1][it * 2 + hi] = (unsigned int)(b1 >> (hi * 32));
        maskl[rbase + 2][it * 2 + hi] = (unsigned int)(b2 >> (hi * 32));
        maskl[rbase + 3][it * 2 + hi] = (unsigned int)(b3 >> (hi * 32));
      }
    }
    float mxs[4] = {mx0, mx1, mx2, mx3};
    #pragma unroll
    for (int rr = 0; rr < 4; ++rr) {
      float ms = mxs[rr];
      #pragma unroll
      for (int d = 1; d < 64; d <<= 1) ms = fmaxf(ms, __shfl_xor(ms, d));
      float s1v = s1g[i0 + rbase + rr];
      float z = s1v + ms;
      float m = (ms <= -3.3e38f) ? NEGINF : (z >= 0.f ? z : LALPHA * z);
      float ls = 0.f;
      for (int it = 0; it < 128; ++it) {
        int jj = it * 64 + lane;
        unsigned int wrd = maskl[rbase + rr][it * 2 + (lane >> 5)];
        float x = s1v + s2l[jj];
        x = (x >= 0.f) ? x : LALPHA * x;
        x = ((wrd >> (lane & 31)) & 1u) ? x : NEGINF;
        ls += __expf(x - m);
      }
      #pragma unroll
      for (int d = 1; d < 64; d <<= 1) ls += __shfl_xor(ls, d);
      if (lane == 0) {
        rowp[rbase + rr][0] = s1v;
        rowp[rbase + rr][1] = m;
        rowp[rbase + rr][2] = 1.f / ls;
      }
    }
  }
  __syncthreads();

  // ---------------- phase 2: attn write + PV via MFMA, K split over waves ---
  const int row = lane & 15;   // A-row of the 16x16x32 fragment
  const int kg = lane >> 4;    // k-block within fragment
  const float s1r = rowp[row][0];
  const float mr = rowp[row][1];
  const float rir = rowp[row][2];
  const int kbase = wv * 2048;
  f32x4 acc0 = {0,0,0,0}, acc1 = {0,0,0,0}, acc2 = {0,0,0,0}, acc3 = {0,0,0,0};
  float* __restrict__ orow = outa + (size_t)(i0 + row) * NN;
  const short8* __restrict__ bfrag = (const short8*)whfh;
  for (int step = 0; step < 64; ++step) {
    const int k0 = kbase + step * 32;
    const int jb = k0 + kg * 8;
    f32x4 sa = *(const f32x4*)&s2l[jb];
    f32x4 sb = *(const f32x4*)&s2l[jb + 4];
    unsigned int bits = maskl[row][k0 >> 5] >> (kg * 8);
    float s2v[8] = {sa.x, sa.y, sa.z, sa.w, sb.x, sb.y, sb.z, sb.w};
    float af[8];
    short8 AH, AL;
    #pragma unroll
    for (int e = 0; e < 8; ++e) {
      float x = s1r + s2v[e];
      x = (x >= 0.f) ? x : LALPHA * x;
      x = ((bits >> e) & 1u) ? x : NEGINF;
      float p = __expf(x - mr) * rir;
      af[e] = p;
      unsigned short hb = f32_to_bf16(p);
      AH[e] = (short)hb;
      AL[e] = (short)f32_to_bf16(p - bf16_to_f32(hb));
    }
    f32x4 st0 = {af[0], af[1], af[2], af[3]};
    f32x4 st1 = {af[4], af[5], af[6], af[7]};
    __builtin_nontemporal_store(st0, (f32x4*)&orow[jb]);
    __builtin_nontemporal_store(st1, (f32x4*)&orow[jb + 4]);
    size_t fb = (size_t)(k0 >> 5) * 256 + lane;  // short8 units
    short8 B0 = bfrag[fb];
    short8 B1 = bfrag[fb + 64];
    short8 B2 = bfrag[fb + 128];
    short8 B3 = bfrag[fb + 192];
    acc0 = __builtin_amdgcn_mfma_f32_16x16x32_bf16(AH, B0, acc0, 0, 0, 0);
    acc1 = __builtin_amdgcn_mfma_f32_16x16x32_bf16(AH, B1, acc1, 0, 0, 0);
    acc2 = __builtin_amdgcn_mfma_f32_16x16x32_bf16(AH, B2, acc2, 0, 0, 0);
    acc3 = __builtin_amdgcn_mfma_f32_16x16x32_bf16(AH, B3, acc3, 0, 0, 0);
    acc0 = __builtin_amdgcn_mfma_f32_16x16x32_bf16(AL, B0, acc0, 0, 0, 0);
    acc1 = __builtin_amdgcn_mfma_f32_16x16x32_bf16(AL, B1, acc1, 0, 0, 0);
    acc2 = __builtin_amdgcn_mfma_f32_16x16x32_bf16(AL, B2, acc2, 0, 0, 0);
    acc3 = __builtin_amdgcn_mfma_f32_16x16x32_bf16(AL, B3, acc3, 0, 0, 0);
  }
  __syncthreads();  // all waves done reading maskl -> reuse as reduce buffer
  float* red = (float*)&maskl[0][0];
  {
    const int c15 = lane & 15;
    f32x4 av[4] = {acc0, acc1, acc2, acc3};
    #pragma unroll
    for (int nt = 0; nt < 4; ++nt) {
      #pragma unroll
      for (int rg = 0; rg < 4; ++rg) {
        // C/D layout: out-row = kg*4+rg, out-col = nt*16 + (lane&15)
        red[wv * 1024 + (kg * 4 + rg) * 64 + nt * 16 + c15] = av[nt][rg];
      }
    }
  }
  __syncthreads();
  {
    int base = tid * 4;
    f32x4 r0 = *(f32x4*)&red[base];
    f32x4 r1 = *(f32x4*)&red[1024 + base];
    f32x4 r2 = *(f32x4*)&red[2048 + base];
    f32x4 r3 = *(f32x4*)&red[3072 + base];
    f32x4 s = r0 + r1 + r2 + r3;
    *(f32x4*)&outh[(size_t)i0 * FOUT + base] = s;
  }
}

extern "C" void kernel_launch(void* const* d_in, const int* in_sizes, int n_in,
                              void* d_out, int out_size, void* d_ws, size_t ws_size,
                              hipStream_t stream) {
  const float* h = (const float*)d_in[0];
  const int* adj = (const int*)d_in[1];
  const float* W = (const float*)d_in[2];
  const float* a = (const float*)d_in[3];
  float* outh = (float*)d_out;                    // h_prime [8192, 64]
  float* outa = outh + (size_t)NN * FOUT;         // attention [8192, 8192]
  char* ws = (char*)d_ws;                         // needs ~1.2 MB
  float* s1g = (float*)ws;
  float* s2g = s1g + NN;
  unsigned short* whfh = (unsigned short*)(ws + 64 * 1024);  // 1 MB B-fragments
  gat_prep<<<512, 256, 0, stream>>>(h, W, a, s1g, s2g, whfh);
  gat_main<<<512, 256, 0, stream>>>(adj, s1g, s2g, whfh, outh, outa);
}